// Round 13
// baseline (359.367 us; speedup 1.0000x reference)
//
#include <hip/hip_runtime.h>
#include <hip/hip_bf16.h>
#include <hip/hip_fp16.h>

// Problem constants (CrossAttention_17076789969260)
// Inputs: fp32 buffers (bf16-rounded values). Output: fp32 buffer.
#define B_    4
#define TQ    2048
#define TKV   2048
#define DM    1024
#define NH    16
#define NKV   4
#define DK    64

typedef _Float16 f16x8 __attribute__((ext_vector_type(8)));
typedef _Float16 f16x4 __attribute__((ext_vector_type(4)));
typedef float    f32x4 __attribute__((ext_vector_type(4)));
typedef float    f32x16 __attribute__((ext_vector_type(16)));

__device__ __forceinline__ void store1(float* p, float v) { *p = v; }
__device__ __forceinline__ void store1(__half* p, float v) {
  union { __half h; unsigned short u; } c; c.h = __float2half(v);
  *(unsigned short*)p = c.u;
}

// pack two fp32 -> 2 x f16 dword (RTZ; exact on bf16-rounded inputs)
__device__ __forceinline__ unsigned pack2h(float a, float b) {
  auto pk = __builtin_amdgcn_cvt_pkrtz(a, b);
  unsigned u;
  __builtin_memcpy(&u, &pk, 4);
  return u;
}

// 4-element fragment loaders for GEMM staging (result: f16x4).
// fp32 path: packed cvt (R12-confirmed: GEMM pool 211 -> 189us).
__device__ __forceinline__ f16x4 load4h(const float* p) {
  float4 v = *(const float4*)p;
  union { unsigned u[2]; f16x4 h; } c;
  c.u[0] = pack2h(v.x, v.y);
  c.u[1] = pack2h(v.z, v.w);
  return c.h;
}
__device__ __forceinline__ f16x4 load4h(const __half* p) {
  return *(const f16x4*)p;  // already f16
}

__global__ void zero_out_kernel(float* out, int n) {
  int i = blockIdx.x * blockDim.x + threadIdx.x;
  if (i < n) out[i] = 0.0f;
}

// ---------- MFMA projection GEMM: C[M,N] = A[M,K] @ W[N,K]^T ----------
// (R12-exact) BM=64 x BN=128 tile, BK=32, 4 waves 2x2 (wave = 32x64,
// 8 mfma/K-step, acc = 32 VGPR). Q-proj grid 1024, ~5 blocks/CU resident.
// Double-buffered LDS + register prefetch per K-step:
// {write regs->LDS[cur]; ONE barrier; issue k+1 loads; ds_read frags; MFMA}.
// fp32->f16 conversion fused into staging (packed cvt, see load4h).
// FUSED 1D-grid decode: bid<1024 -> Q-proj tile (A0,W0,C0, N0, bx<8);
// next 256 -> K-proj (A1,W1,C1, Nkv, bx<2); next 256 -> V-proj (A1,W2,C2).
// The out-proj launch uses grid=1024 (z=0 path only, AT=__half, CT=float).
#define GAP 40
#define BM 64
#define BN 128
template <typename AT, typename CT>
__global__ __launch_bounds__(256) void gemm_proj(
    const AT* __restrict__ A0, const AT* __restrict__ A1,
    const float* __restrict__ W0, const float* __restrict__ W1,
    const float* __restrict__ W2,
    CT* __restrict__ C0, CT* __restrict__ C1, CT* __restrict__ C2,
    int N0, int Nkv, int K) {
  const int bid = blockIdx.x;
  const AT* __restrict__ A;
  const float* __restrict__ W;
  CT* __restrict__ C;
  int N, bx, by;
  if (bid < 1024) {
    A = A0; W = W0; C = C0; N = N0;
    bx = bid & 7; by = bid >> 3;
  } else {
    int r = bid - 1024;
    A = A1; N = Nkv;
    if (r < 256) { W = W1; C = C1; } else { W = W2; C = C2; r -= 256; }
    bx = r & 1; by = r >> 1;
  }

  __shared__ _Float16 As[2 * BM * GAP];
  __shared__ _Float16 Ws[2 * BN * GAP];

  const int t = threadIdx.x;
  const int w = t >> 6, l = t & 63;
  const int lm = l & 15, quad = l >> 4;
  const int wm = (w >> 1) * 32, wn = (w & 1) * 64;
  const int m0 = by * BM, n0 = bx * BN;

  // staging: 8 lanes per 32-elem row; 32 rows/pass; A 2 passes, W 4 passes
  const int srow = t >> 3;        // 0..31
  const int scol = (t & 7) * 4;   // 0,4,..,28

  f32x4 acc[2][4] = {};
  f16x4 av[2], wv[4];
  // prologue: K-step 0 into regs
#pragma unroll
  for (int p = 0; p < 2; ++p)
    av[p] = load4h(&A[(size_t)(m0 + srow + p * 32) * K + scol]);
#pragma unroll
  for (int p = 0; p < 4; ++p)
    wv[p] = load4h(&W[(size_t)(n0 + srow + p * 32) * K + scol]);

  int cur = 0;
  for (int k0 = 0; k0 < K; k0 += 32) {
    _Float16* as = &As[cur * BM * GAP];
    _Float16* ws = &Ws[cur * BN * GAP];
#pragma unroll
    for (int p = 0; p < 2; ++p)
      *(f16x4*)&as[(srow + p * 32) * GAP + scol] = av[p];
#pragma unroll
    for (int p = 0; p < 4; ++p)
      *(f16x4*)&ws[(srow + p * 32) * GAP + scol] = wv[p];
    __syncthreads();
    // issue next K-step's loads; latency hides under frag reads + MFMA
    if (k0 + 32 < K) {
#pragma unroll
      for (int p = 0; p < 2; ++p)
        av[p] = load4h(&A[(size_t)(m0 + srow + p * 32) * K + k0 + 32 + scol]);
#pragma unroll
      for (int p = 0; p < 4; ++p)
        wv[p] = load4h(&W[(size_t)(n0 + srow + p * 32) * K + k0 + 32 + scol]);
    }

    f16x8 af[2], bf[4];
#pragma unroll
    for (int i = 0; i < 2; ++i)
      af[i] = *(const f16x8*)&as[(wm + i * 16 + lm) * GAP + quad * 8];
#pragma unroll
    for (int j = 0; j < 4; ++j)
      bf[j] = *(const f16x8*)&ws[(wn + j * 16 + lm) * GAP + quad * 8];
#pragma unroll
    for (int i = 0; i < 2; ++i)
#pragma unroll
      for (int j = 0; j < 4; ++j)
        acc[i][j] =
            __builtin_amdgcn_mfma_f32_16x16x32_f16(af[i], bf[j], acc[i][j], 0, 0, 0);
    cur ^= 1;
  }

  // C/D frag: lane holds D[row=quad*4+r][col=lm] per 16x16 tile
#pragma unroll
  for (int i = 0; i < 2; ++i)
#pragma unroll
    for (int r = 0; r < 4; ++r) {
      size_t row = (size_t)(m0 + wm + i * 16 + quad * 4 + r) * N;
#pragma unroll
      for (int j = 0; j < 4; ++j)
        store1(&C[row + n0 + wn + j * 16 + lm], acc[i][j][r]);
    }
}

// ---------- RoPE in place on fp16 [B*T, H, 64]; position = row % T ----------
// (used for K only; Q-rope is fused into attn_mfma's register load)
__global__ void rope_kernel(__half* __restrict__ X, int T, int H, int total_pairs) {
  int idx = blockIdx.x * blockDim.x + threadIdx.x;
  if (idx >= total_pairs) return;
  int i   = idx & 31;
  int h   = (idx >> 5) % H;
  int row = idx / (32 * H);
  int tpos = row % T;
  __half* p = X + ((size_t)row * H + h) * DK;
  // 10000^(-i/32) = exp2(-i * log2(10000)/32)
  float inv = exp2f((float)i * -0.41524101186091403f);
  float ang = (float)tpos * inv;
  float c, s;
  sincosf(ang, &s, &c);
  float x1 = __half2float(p[i]), x2 = __half2float(p[i + 32]);
  p[i]      = __float2half(x1 * c - x2 * s);
  p[i + 32] = __float2half(x2 * c + x1 * s);
}

// ---------- MFMA flash attention, 32x32 frags, swapped QK^T ----------
// (R7-exact: measured 144.6us; the best-measured structure is 2-tile with
// both f32x16 st live -- more MFMA ILP, batched softmax/PV; R10-12's
// tile-at-a-time "trim" measured 150-170us and is abandoned.)
// Block = 4 waves (256 thr) = 128 q rows; wave w owns rows [qt*128+w*32, +32).
// mfma_f32_32x32x16_f16 layouts:
//   A-frag: lane holds A[m=lane&31][k=8*(lane>>5)+j], j=0..7
//   B-frag: lane holds B[k=8*(lane>>5)+j][n=lane&31]
//   C/D   : lane holds D[row=(reg&3)+8*(reg>>2)+4*(lane>>5)][col=lane&31]
// Swapped QK^T: st = mfma(A=K, B=Q) = S^T[key][q]; each lane holds 32 scores
// of column q=lane&31 -> row-max is in-lane reduce + one shfl_xor(32).
// P stays in REGISTERS: cvt_pkrtz pack -> one half-swap (shfl_xor 32) per
// dword-pair redistributes into PV A-frags (P[q][key]); no P LDS buffer.
// l = row-sums via ones-B-frag MFMA (row space, matches o_acc).
// Defer-rescale (T13, THR=8 -> P<=256, f16-safe).
// Q-RoPE fused: lane holds its full 64-d q-row across aq[0..3]; rope pair
// (d, d+32) lives at (kc, kc+2) same j -> in-register rotate, once/kernel.
// O aliases Q safely: wave reads only its own q rows first, writes them last.
#define AP 72  // LDS pitch (f16): 144B rows -> b128-aligned, balanced banks
#define C2 0.18033688011112042f  // 0.125 * log2(e): softmax in base-2 domain
#define RLOG2 -0.41524101186091403f  // -log2(10000)/32
__global__ __launch_bounds__(256, 2) void attn_mfma(const __half* Q,
                                                    const __half* __restrict__ K,
                                                    const __half* __restrict__ V,
                                                    __half* O) {
  __shared__ _Float16 Ks[64 * AP];        // [key][d]
  __shared__ _Float16 Vt[64 * AP];        // [d][key]
  const int t = threadIdx.x;
  const int w = t >> 6, l = t & 63;
  const int lq = l & 31, hi = l >> 5;
  const int qt = blockIdx.x, h = blockIdx.y, b = blockIdx.z;
  const int kvh = h >> 2;

  // Q B-frags (registers, whole kernel): aq[kc] = Q[qrow][kc*16+8*hi+j]
  const __half* qbase =
      Q + (((size_t)b * TQ + qt * 128 + w * 32 + lq) * NH + h) * DK;
  f16x8 aq[4];
#pragma unroll
  for (int kc = 0; kc < 4; ++kc)
    aq[kc] = *(const f16x8*)(qbase + kc * 16 + hi * 8);

  // fused RoPE on Q (in-register): pair (d, d+32) = (aq[kc][j], aq[kc+2][j])
  {
    const float tpos = (float)(qt * 128 + w * 32 + lq);
#pragma unroll
    for (int kc = 0; kc < 2; ++kc)
#pragma unroll
      for (int j = 0; j < 8; ++j) {
        int d = kc * 16 + hi * 8 + j;
        float inv = exp2f((float)d * RLOG2);
        float ang = tpos * inv;
        float c, s;
        sincosf(ang, &s, &c);
        float x1 = (float)aq[kc][j], x2 = (float)aq[kc + 2][j];
        aq[kc][j]     = (_Float16)(x1 * c - x2 * s);
        aq[kc + 2][j] = (_Float16)(x2 * c + x1 * s);
      }
  }

  const f16x8 vones = {1.f16, 1.f16, 1.f16, 1.f16, 1.f16, 1.f16, 1.f16, 1.f16};

  // staging: 2 x 16B units per thread for K and V each (64x64 f16 tiles)
  const int skey = t >> 3, sdseg = t & 7;          // K [key][d], +32 keys r=1
  const int vkey = t & 63, vdb0 = (t >> 6) * 8;    // V -> Vt [d][key], +32 d r=1
  const __half* kp0 =
      K + (((size_t)b * TKV + skey) * NKV + kvh) * DK + sdseg * 8;
  const __half* kp1 = kp0 + (size_t)32 * NKV * DK;
  const __half* vp0 =
      V + (((size_t)b * TKV + vkey) * NKV + kvh) * DK + vdb0;
  const __half* vp1 = vp0 + 32;
  const size_t kstep = (size_t)64 * NKV * DK;  // 64 keys forward

  f16x8 kpre0 = *(const f16x8*)kp0, kpre1 = *(const f16x8*)kp1;
  f16x8 vpre0 = *(const f16x8*)vp0, vpre1 = *(const f16x8*)vp1;

  f32x16 o_acc[2], l_acc;
#pragma unroll
  for (int i = 0; i < 16; ++i) { o_acc[0][i] = 0.f; o_acc[1][i] = 0.f; l_acc[i] = 0.f; }
  float m_run = -1e30f;

  for (int ck = 0; ck < TKV / 64; ++ck) {
    __syncthreads();  // prior chunk's Ks/Vt reads done
    *(f16x8*)&Ks[skey * AP + sdseg * 8] = kpre0;
    *(f16x8*)&Ks[(skey + 32) * AP + sdseg * 8] = kpre1;
#pragma unroll
    for (int j = 0; j < 8; ++j) {
      Vt[(vdb0 + j) * AP + vkey] = vpre0[j];
      Vt[(vdb0 + 32 + j) * AP + vkey] = vpre1[j];
    }
    __syncthreads();
    // T14: issue next chunk's loads now; latency hides under compute below
    if (ck + 1 < TKV / 64) {
      size_t off = (size_t)(ck + 1) * kstep;
      kpre0 = *(const f16x8*)(kp0 + off);
      kpre1 = *(const f16x8*)(kp1 + off);
      vpre0 = *(const f16x8*)(vp0 + off);
      vpre1 = *(const f16x8*)(vp1 + off);
    }

    // S^T = K Q^T : st[tile] covers keys [tile*32, +32) x 32 q-cols
    f32x16 st[2];
#pragma unroll
    for (int i = 0; i < 16; ++i) { st[0][i] = 0.f; st[1][i] = 0.f; }
    __builtin_amdgcn_s_setprio(1);
#pragma unroll
    for (int tile = 0; tile < 2; ++tile)
#pragma unroll
      for (int kc = 0; kc < 4; ++kc) {
        f16x8 ak =
            *(const f16x8*)&Ks[(tile * 32 + lq) * AP + kc * 16 + hi * 8];
        st[tile] =
            __builtin_amdgcn_mfma_f32_32x32x16_f16(ak, aq[kc], st[tile], 0, 0, 0);
      }
    __builtin_amdgcn_s_setprio(0);

    // column max (q = lane&31): in-lane over 32 regs, then swap halves
    float vmax = st[0][0];
#pragma unroll
    for (int i = 1; i < 16; ++i) vmax = fmaxf(vmax, st[0][i]);
#pragma unroll
    for (int i = 0; i < 16; ++i) vmax = fmaxf(vmax, st[1][i]);
    vmax *= C2;
    vmax = fmaxf(vmax, __shfl_xor(vmax, 32));

    // T13 defer-rescale: only pay when max grew past THR
    if (!__all(vmax - m_run <= 8.0f)) {
      float m_new = fmaxf(m_run, vmax);
      float alpha = exp2f(m_run - m_new);  // column space (q = lane&31)
      m_run = m_new;
#pragma unroll
      for (int reg = 0; reg < 16; ++reg) {
        int row = (reg & 3) + 8 * (reg >> 2) + 4 * hi;
        float ar = __shfl(alpha, row);     // alpha for q-row of this reg
        l_acc[reg] *= ar;
        o_acc[0][reg] *= ar;
        o_acc[1][reg] *= ar;
      }
    }

    // P = 2^(st*C2 - m), packed to f16 pairs (consecutive keys)
    unsigned q16u[2][8];
#pragma unroll
    for (int tile = 0; tile < 2; ++tile)
#pragma unroll
      for (int rr = 0; rr < 8; ++rr) {
        float p0 = exp2f(st[tile][2 * rr] * C2 - m_run);
        float p1 = exp2f(st[tile][2 * rr + 1] * C2 - m_run);
        q16u[tile][rr] = pack2h(p0, p1);
      }

    // Redistribute P^T (column space) -> PV A-frags (row space) and O += P V.
    __builtin_amdgcn_s_setprio(1);
#pragma unroll
    for (int kb = 0; kb < 4; ++kb) {
      const int tl = kb >> 1, base = (kb & 1) * 4;
      union { unsigned u[4]; f16x8 v; } ap;
#pragma unroll
      for (int c = 0; c < 2; ++c) {
        unsigned R0 = q16u[tl][base + c];       // reg wanted by hi_t=0
        unsigned R1 = q16u[tl][base + 2 + c];   // reg wanted by hi_t=1
        unsigned Z = hi ? R0 : R1;              // what my partner wants
        unsigned Xp = __shfl_xor(Z, 32);        // partner's Z (what I want)
        ap.u[c]     = hi ? Xp : R0;             // from hi=0 half
        ap.u[c + 2] = hi ? R1 : Xp;             // from hi=1 half
      }
      l_acc = __builtin_amdgcn_mfma_f32_32x32x16_f16(ap.v, vones, l_acc, 0, 0, 0);
#pragma unroll
      for (int nt = 0; nt < 2; ++nt) {
        f16x8 bv = *(const f16x8*)&Vt[(nt * 32 + lq) * AP + kb * 16 + hi * 8];
        o_acc[nt] =
            __builtin_amdgcn_mfma_f32_32x32x16_f16(ap.v, bv, o_acc[nt], 0, 0, 0);
      }
    }
    __builtin_amdgcn_s_setprio(0);
  }

  // epilogue: row = (reg&3)+8*(reg>>2)+4*hi, cols d = nt*32 + lq
#pragma unroll
  for (int reg = 0; reg < 16; ++reg) {
    int row = (reg & 3) + 8 * (reg >> 2) + 4 * hi;
    float inv = 1.0f / l_acc[reg];
    size_t orow =
        (((size_t)b * TQ + qt * 128 + w * 32 + row) * NH + h) * DK;
    O[orow + lq]      = __float2half(o_acc[0][reg] * inv);
    O[orow + 32 + lq] = __float2half(o_acc[1][reg] * inv);
  }
}

extern "C" void kernel_launch(void* const* d_in, const int* in_sizes, int n_in,
                              void* d_out, int out_size, void* d_ws, size_t ws_size,
                              hipStream_t stream) {
  // ---- Input mapping via in_sizes pattern (dict vs sorted-key order) ----
  int iq, ikv, iwq, iwk, iwv, iwo;
  bool ok = true;
  if (n_in >= 8 && in_sizes[0] == 8388608 && in_sizes[1] == 8388608) {
    iq = 0; ikv = 1; iwq = 4; iwk = 5; iwv = 6; iwo = 7;          // dict order
  } else if (n_in >= 8 && in_sizes[0] == 8388608 && in_sizes[1] == 8192) {
    ikv = 0; iq = 2; iwk = 4; iwo = 5; iwq = 6; iwv = 7;          // sorted keys
  } else if (n_in == 6 && in_sizes[2] == 1048576) {
    iq = 0; ikv = 1; iwq = 2; iwk = 3; iwv = 4; iwo = 5;          // dict, no masks
  } else if (n_in == 6 && in_sizes[2] == 262144) {
    ikv = 0; iq = 1; iwk = 2; iwo = 3; iwq = 4; iwv = 5;          // sorted, no masks
  } else {
    ok = false; iq = ikv = iwq = iwk = iwv = iwo = 0;
  }

  const size_t nQ  = (size_t)B_ * TQ * DM;
  const size_t nKV = (size_t)B_ * TKV * NKV * DK;
  const size_t need = (nQ + 2 * nKV) * sizeof(__half);  // 24 MB
  if (!ok || ws_size < need) {
    zero_out_kernel<<<(out_size + 255) / 256, 256, 0, stream>>>((float*)d_out,
                                                                out_size);
    return;
  }

  const float* query     = (const float*)d_in[iq];
  const float* key_value = (const float*)d_in[ikv];
  const float* w_q   = (const float*)d_in[iwq];
  const float* w_k   = (const float*)d_in[iwk];
  const float* w_v   = (const float*)d_in[iwv];
  const float* w_out = (const float*)d_in[iwo];
  float* out = (float*)d_out;

  __half* Qh = (__half*)d_ws;
  __half* Kh = Qh + nQ;
  __half* Vh = Kh + nKV;

  dim3 blk(256);
  // Fused Q/K/V projections, one 1536-block launch:
  // bid<1024: Q-proj (M=8192,N=1024); +256: K-proj; +256: V-proj (N=256).
  gemm_proj<<<dim3(1536), blk, 0, stream>>>(query, key_value, w_q, w_k, w_v,
                                            Qh, Kh, Vh, DM, NKV * DK, DM);
  int pk = B_ * TKV * NKV * 32;
  rope_kernel<<<(pk + 255) / 256, blk, 0, stream>>>(Kh, TKV, NKV, pk);
  // MFMA flash attention (32x32 frags, P-in-register, fused Q-rope)
  attn_mfma<<<dim3(TQ / 128, NH, B_), dim3(256), 0, stream>>>(Qh, Kh, Vh, Qh);
  // Output projection: M=8192, N=1024, K=1024, fp32 out (f16 A input);
  // grid 1024 -> z=0 path only.
  gemm_proj<<<dim3(1024), blk, 0, stream>>>(Qh, Qh, w_out, w_out, w_out,
                                            out, out, out, DM, DM, DM);
}

// Round 14
// 351.392 us; speedup vs baseline: 1.0227x; 1.0227x over previous
//
#include <hip/hip_runtime.h>
#include <hip/hip_bf16.h>
#include <hip/hip_fp16.h>

// Problem constants (CrossAttention_17076789969260)
// Inputs: fp32 buffers (bf16-rounded values). Output: fp32 buffer.
#define B_    4
#define TQ    2048
#define TKV   2048
#define DM    1024
#define NH    16
#define NKV   4
#define DK    64

typedef _Float16 f16x8 __attribute__((ext_vector_type(8)));
typedef _Float16 f16x4 __attribute__((ext_vector_type(4)));
typedef float    f32x4 __attribute__((ext_vector_type(4)));
typedef float    f32x16 __attribute__((ext_vector_type(16)));

template <typename T> struct IsHalf { static constexpr bool v = false; };
template <> struct IsHalf<__half> { static constexpr bool v = true; };

__device__ __forceinline__ void store1(float* p, float v) { *p = v; }
__device__ __forceinline__ void store1(__half* p, float v) {
  union { __half h; unsigned short u; } c; c.h = __float2half(v);
  *(unsigned short*)p = c.u;
}

// pack two fp32 -> 2 x f16 dword (RTZ; exact on bf16-rounded inputs)
__device__ __forceinline__ unsigned pack2h(float a, float b) {
  auto pk = __builtin_amdgcn_cvt_pkrtz(a, b);
  unsigned u;
  __builtin_memcpy(&u, &pk, 4);
  return u;
}

// 4-element fragment loaders for GEMM staging (result: f16x4).
__device__ __forceinline__ f16x4 load4h(const float* p) {
  float4 v = *(const float4*)p;
  union { unsigned u[2]; f16x4 h; } c;
  c.u[0] = pack2h(v.x, v.y);
  c.u[1] = pack2h(v.z, v.w);
  return c.h;
}

__global__ void zero_out_kernel(float* out, int n) {
  int i = blockIdx.x * blockDim.x + threadIdx.x;
  if (i < n) out[i] = 0.0f;
}

// ---------- one-shot fp32->f16 weight conversion ----------
// R14: weights were being re-converted fp32->f16 in EVERY K-step of every
// GEMM tile (8 pack2h/thread/K-step). Hoist to one pass: 2.62M elems
// (w_q 1M | w_k 256K | w_v 256K | w_out 1M), one granule of 8 per thread.
#define GQ  131072  // w_q granules (DM*DM/8)
#define GKV 32768   // w_k (and w_v) granules
__global__ __launch_bounds__(256) void cvt_weights(
    const float* __restrict__ wq, const float* __restrict__ wk,
    const float* __restrict__ wv, const float* __restrict__ wo,
    __half* __restrict__ dq, __half* __restrict__ dk,
    __half* __restrict__ dv, __half* __restrict__ dpo) {
  int i = blockIdx.x * 256 + threadIdx.x;
  const float* src;
  __half* dst;
  int off;
  if (i < GQ)                { src = wq; dst = dq;  off = i; }
  else if (i < GQ + GKV)     { src = wk; dst = dk;  off = i - GQ; }
  else if (i < GQ + 2 * GKV) { src = wv; dst = dv;  off = i - GQ - GKV; }
  else                       { src = wo; dst = dpo; off = i - GQ - 2 * GKV; }
  const float4* p = (const float4*)src + 2 * (size_t)off;
  float4 a = p[0], b = p[1];
  union { unsigned u[4]; f16x8 h; } c;
  c.u[0] = pack2h(a.x, a.y); c.u[1] = pack2h(a.z, a.w);
  c.u[2] = pack2h(b.x, b.y); c.u[3] = pack2h(b.z, b.w);
  *(f16x8*)(dst + 8 * (size_t)off) = c.h;
}

// ---------- MFMA projection GEMM: C[M,N] = A[M,K] @ W[N,K]^T ----------
// BM=64 x BN=128 tile, BK=32, 4 waves 2x2 (wave = 32x64, 8 mfma/K-step).
// Double-buffered LDS + register prefetch per K-step:
// {write regs->LDS[cur]; ONE barrier; issue k+1 loads; ds_read frags; MFMA}.
// W is ALWAYS f16 now (pre-converted): 2 x f16x8 loads + b128 LDS writes,
// zero cvt in the loop. A: f16 path 1 x f16x8 load; fp32 path float4+pack2h.
// FUSED 1D-grid decode: bid<1024 -> Q-proj tile (A0,W0,C0, N0, bx<8);
// next 256 -> K-proj (A1,W1,C1, Nkv, bx<2); next 256 -> V-proj (A1,W2,C2).
// The out-proj launch uses grid=1024 (z=0 path only, AT=__half, CT=float).
#define GAP 40
#define BM 64
#define BN 128
template <typename AT, typename CT>
__global__ __launch_bounds__(256) void gemm_proj(
    const AT* __restrict__ A0, const AT* __restrict__ A1,
    const __half* __restrict__ W0, const __half* __restrict__ W1,
    const __half* __restrict__ W2,
    CT* __restrict__ C0, CT* __restrict__ C1, CT* __restrict__ C2,
    int N0, int Nkv, int K) {
  const int bid = blockIdx.x;
  const AT* __restrict__ A;
  const __half* __restrict__ W;
  CT* __restrict__ C;
  int N, bx, by;
  if (bid < 1024) {
    A = A0; W = W0; C = C0; N = N0;
    bx = bid & 7; by = bid >> 3;
  } else {
    int r = bid - 1024;
    A = A1; N = Nkv;
    if (r < 256) { W = W1; C = C1; } else { W = W2; C = C2; r -= 256; }
    bx = r & 1; by = r >> 1;
  }

  __shared__ _Float16 As[2 * BM * GAP];
  __shared__ _Float16 Ws[2 * BN * GAP];

  const int t = threadIdx.x;
  const int w = t >> 6, l = t & 63;
  const int lm = l & 15, quad = l >> 4;
  const int wm = (w >> 1) * 32, wn = (w & 1) * 64;
  const int m0 = by * BM, n0 = bx * BN;

  // staging geometries
  const int srow = t >> 3, scol = (t & 7) * 4;  // fp32 A: 8 lanes/32-col row
  const int hrow = t >> 2, hcol = (t & 3) * 8;  // f16   : 4 lanes/32-col row

  f32x4 acc[2][4] = {};
  f16x4 av4[2];
  f16x8 av8, wv8[2];

  auto loadA = [&](int k0) {
    if constexpr (IsHalf<AT>::v) {
      av8 = *(const f16x8*)&A[(size_t)(m0 + hrow) * K + k0 + hcol];
    } else {
#pragma unroll
      for (int p = 0; p < 2; ++p)
        av4[p] = load4h(&A[(size_t)(m0 + srow + p * 32) * K + k0 + scol]);
    }
  };
  auto storeA = [&](_Float16* as) {
    if constexpr (IsHalf<AT>::v) {
      *(f16x8*)&as[hrow * GAP + hcol] = av8;
    } else {
#pragma unroll
      for (int p = 0; p < 2; ++p)
        *(f16x4*)&as[(srow + p * 32) * GAP + scol] = av4[p];
    }
  };
  auto loadW = [&](int k0) {
#pragma unroll
    for (int p = 0; p < 2; ++p)
      wv8[p] = *(const f16x8*)&W[(size_t)(n0 + hrow + p * 64) * K + k0 + hcol];
  };
  auto storeW = [&](_Float16* ws) {
#pragma unroll
    for (int p = 0; p < 2; ++p)
      *(f16x8*)&ws[(hrow + p * 64) * GAP + hcol] = wv8[p];
  };

  loadA(0);
  loadW(0);
  int cur = 0;
  for (int k0 = 0; k0 < K; k0 += 32) {
    _Float16* as = &As[cur * BM * GAP];
    _Float16* ws = &Ws[cur * BN * GAP];
    storeA(as);
    storeW(ws);
    __syncthreads();
    // issue next K-step's loads; latency hides under frag reads + MFMA
    if (k0 + 32 < K) { loadA(k0 + 32); loadW(k0 + 32); }

    f16x8 af[2], bf[4];
#pragma unroll
    for (int i = 0; i < 2; ++i)
      af[i] = *(const f16x8*)&as[(wm + i * 16 + lm) * GAP + quad * 8];
#pragma unroll
    for (int j = 0; j < 4; ++j)
      bf[j] = *(const f16x8*)&ws[(wn + j * 16 + lm) * GAP + quad * 8];
#pragma unroll
    for (int i = 0; i < 2; ++i)
#pragma unroll
      for (int j = 0; j < 4; ++j)
        acc[i][j] =
            __builtin_amdgcn_mfma_f32_16x16x32_f16(af[i], bf[j], acc[i][j], 0, 0, 0);
    cur ^= 1;
  }

  // C/D frag: lane holds D[row=quad*4+r][col=lm] per 16x16 tile
#pragma unroll
  for (int i = 0; i < 2; ++i)
#pragma unroll
    for (int r = 0; r < 4; ++r) {
      size_t row = (size_t)(m0 + wm + i * 16 + quad * 4 + r) * N;
#pragma unroll
      for (int j = 0; j < 4; ++j)
        store1(&C[row + n0 + wn + j * 16 + lm], acc[i][j][r]);
    }
}

// ---------- RoPE in place on fp16 [B*T, H, 64]; position = row % T ----------
// (used for K only; Q-rope is fused into attn_mfma's register load)
__global__ void rope_kernel(__half* __restrict__ X, int T, int H, int total_pairs) {
  int idx = blockIdx.x * blockDim.x + threadIdx.x;
  if (idx >= total_pairs) return;
  int i   = idx & 31;
  int h   = (idx >> 5) % H;
  int row = idx / (32 * H);
  int tpos = row % T;
  __half* p = X + ((size_t)row * H + h) * DK;
  // 10000^(-i/32) = exp2(-i * log2(10000)/32)
  float inv = exp2f((float)i * -0.41524101186091403f);
  float ang = (float)tpos * inv;
  float c, s;
  sincosf(ang, &s, &c);
  float x1 = __half2float(p[i]), x2 = __half2float(p[i + 32]);
  p[i]      = __float2half(x1 * c - x2 * s);
  p[i + 32] = __float2half(x2 * c + x1 * s);
}

// ---------- MFMA flash attention, 32x32 frags, swapped QK^T ----------
// (R13-exact = R7 structure, measured 144.6-146us: 2-tile, both f32x16 st
// live, ones-MFMA l_acc, fused Q-rope, (256,2).)
#define AP 72  // LDS pitch (f16): 144B rows -> b128-aligned, balanced banks
#define C2 0.18033688011112042f  // 0.125 * log2(e): softmax in base-2 domain
#define RLOG2 -0.41524101186091403f  // -log2(10000)/32
__global__ __launch_bounds__(256, 2) void attn_mfma(const __half* Q,
                                                    const __half* __restrict__ K,
                                                    const __half* __restrict__ V,
                                                    __half* O) {
  __shared__ _Float16 Ks[64 * AP];        // [key][d]
  __shared__ _Float16 Vt[64 * AP];        // [d][key]
  const int t = threadIdx.x;
  const int w = t >> 6, l = t & 63;
  const int lq = l & 31, hi = l >> 5;
  const int qt = blockIdx.x, h = blockIdx.y, b = blockIdx.z;
  const int kvh = h >> 2;

  // Q B-frags (registers, whole kernel): aq[kc] = Q[qrow][kc*16+8*hi+j]
  const __half* qbase =
      Q + (((size_t)b * TQ + qt * 128 + w * 32 + lq) * NH + h) * DK;
  f16x8 aq[4];
#pragma unroll
  for (int kc = 0; kc < 4; ++kc)
    aq[kc] = *(const f16x8*)(qbase + kc * 16 + hi * 8);

  // fused RoPE on Q (in-register): pair (d, d+32) = (aq[kc][j], aq[kc+2][j])
  {
    const float tpos = (float)(qt * 128 + w * 32 + lq);
#pragma unroll
    for (int kc = 0; kc < 2; ++kc)
#pragma unroll
      for (int j = 0; j < 8; ++j) {
        int d = kc * 16 + hi * 8 + j;
        float inv = exp2f((float)d * RLOG2);
        float ang = tpos * inv;
        float c, s;
        sincosf(ang, &s, &c);
        float x1 = (float)aq[kc][j], x2 = (float)aq[kc + 2][j];
        aq[kc][j]     = (_Float16)(x1 * c - x2 * s);
        aq[kc + 2][j] = (_Float16)(x2 * c + x1 * s);
      }
  }

  const f16x8 vones = {1.f16, 1.f16, 1.f16, 1.f16, 1.f16, 1.f16, 1.f16, 1.f16};

  // staging: 2 x 16B units per thread for K and V each (64x64 f16 tiles)
  const int skey = t >> 3, sdseg = t & 7;          // K [key][d], +32 keys r=1
  const int vkey = t & 63, vdb0 = (t >> 6) * 8;    // V -> Vt [d][key], +32 d r=1
  const __half* kp0 =
      K + (((size_t)b * TKV + skey) * NKV + kvh) * DK + sdseg * 8;
  const __half* kp1 = kp0 + (size_t)32 * NKV * DK;
  const __half* vp0 =
      V + (((size_t)b * TKV + vkey) * NKV + kvh) * DK + vdb0;
  const __half* vp1 = vp0 + 32;
  const size_t kstep = (size_t)64 * NKV * DK;  // 64 keys forward

  f16x8 kpre0 = *(const f16x8*)kp0, kpre1 = *(const f16x8*)kp1;
  f16x8 vpre0 = *(const f16x8*)vp0, vpre1 = *(const f16x8*)vp1;

  f32x16 o_acc[2], l_acc;
#pragma unroll
  for (int i = 0; i < 16; ++i) { o_acc[0][i] = 0.f; o_acc[1][i] = 0.f; l_acc[i] = 0.f; }
  float m_run = -1e30f;

  for (int ck = 0; ck < TKV / 64; ++ck) {
    __syncthreads();  // prior chunk's Ks/Vt reads done
    *(f16x8*)&Ks[skey * AP + sdseg * 8] = kpre0;
    *(f16x8*)&Ks[(skey + 32) * AP + sdseg * 8] = kpre1;
#pragma unroll
    for (int j = 0; j < 8; ++j) {
      Vt[(vdb0 + j) * AP + vkey] = vpre0[j];
      Vt[(vdb0 + 32 + j) * AP + vkey] = vpre1[j];
    }
    __syncthreads();
    // T14: issue next chunk's loads now; latency hides under compute below
    if (ck + 1 < TKV / 64) {
      size_t off = (size_t)(ck + 1) * kstep;
      kpre0 = *(const f16x8*)(kp0 + off);
      kpre1 = *(const f16x8*)(kp1 + off);
      vpre0 = *(const f16x8*)(vp0 + off);
      vpre1 = *(const f16x8*)(vp1 + off);
    }

    // S^T = K Q^T : st[tile] covers keys [tile*32, +32) x 32 q-cols
    f32x16 st[2];
#pragma unroll
    for (int i = 0; i < 16; ++i) { st[0][i] = 0.f; st[1][i] = 0.f; }
    __builtin_amdgcn_s_setprio(1);
#pragma unroll
    for (int tile = 0; tile < 2; ++tile)
#pragma unroll
      for (int kc = 0; kc < 4; ++kc) {
        f16x8 ak =
            *(const f16x8*)&Ks[(tile * 32 + lq) * AP + kc * 16 + hi * 8];
        st[tile] =
            __builtin_amdgcn_mfma_f32_32x32x16_f16(ak, aq[kc], st[tile], 0, 0, 0);
      }
    __builtin_amdgcn_s_setprio(0);

    // column max (q = lane&31): in-lane over 32 regs, then swap halves
    float vmax = st[0][0];
#pragma unroll
    for (int i = 1; i < 16; ++i) vmax = fmaxf(vmax, st[0][i]);
#pragma unroll
    for (int i = 0; i < 16; ++i) vmax = fmaxf(vmax, st[1][i]);
    vmax *= C2;
    vmax = fmaxf(vmax, __shfl_xor(vmax, 32));

    // T13 defer-rescale: only pay when max grew past THR
    if (!__all(vmax - m_run <= 8.0f)) {
      float m_new = fmaxf(m_run, vmax);
      float alpha = exp2f(m_run - m_new);  // column space (q = lane&31)
      m_run = m_new;
#pragma unroll
      for (int reg = 0; reg < 16; ++reg) {
        int row = (reg & 3) + 8 * (reg >> 2) + 4 * hi;
        float ar = __shfl(alpha, row);     // alpha for q-row of this reg
        l_acc[reg] *= ar;
        o_acc[0][reg] *= ar;
        o_acc[1][reg] *= ar;
      }
    }

    // P = 2^(st*C2 - m), packed to f16 pairs (consecutive keys)
    unsigned q16u[2][8];
#pragma unroll
    for (int tile = 0; tile < 2; ++tile)
#pragma unroll
      for (int rr = 0; rr < 8; ++rr) {
        float p0 = exp2f(st[tile][2 * rr] * C2 - m_run);
        float p1 = exp2f(st[tile][2 * rr + 1] * C2 - m_run);
        q16u[tile][rr] = pack2h(p0, p1);
      }

    // Redistribute P^T (column space) -> PV A-frags (row space) and O += P V.
    __builtin_amdgcn_s_setprio(1);
#pragma unroll
    for (int kb = 0; kb < 4; ++kb) {
      const int tl = kb >> 1, base = (kb & 1) * 4;
      union { unsigned u[4]; f16x8 v; } ap;
#pragma unroll
      for (int c = 0; c < 2; ++c) {
        unsigned R0 = q16u[tl][base + c];       // reg wanted by hi_t=0
        unsigned R1 = q16u[tl][base + 2 + c];   // reg wanted by hi_t=1
        unsigned Z = hi ? R0 : R1;              // what my partner wants
        unsigned Xp = __shfl_xor(Z, 32);        // partner's Z (what I want)
        ap.u[c]     = hi ? Xp : R0;             // from hi=0 half
        ap.u[c + 2] = hi ? R1 : Xp;             // from hi=1 half
      }
      l_acc = __builtin_amdgcn_mfma_f32_32x32x16_f16(ap.v, vones, l_acc, 0, 0, 0);
#pragma unroll
      for (int nt = 0; nt < 2; ++nt) {
        f16x8 bv = *(const f16x8*)&Vt[(nt * 32 + lq) * AP + kb * 16 + hi * 8];
        o_acc[nt] =
            __builtin_amdgcn_mfma_f32_32x32x16_f16(ap.v, bv, o_acc[nt], 0, 0, 0);
      }
    }
    __builtin_amdgcn_s_setprio(0);
  }

  // epilogue: row = (reg&3)+8*(reg>>2)+4*hi, cols d = nt*32 + lq
#pragma unroll
  for (int reg = 0; reg < 16; ++reg) {
    int row = (reg & 3) + 8 * (reg >> 2) + 4 * hi;
    float inv = 1.0f / l_acc[reg];
    size_t orow =
        (((size_t)b * TQ + qt * 128 + w * 32 + row) * NH + h) * DK;
    O[orow + lq]      = __float2half(o_acc[0][reg] * inv);
    O[orow + 32 + lq] = __float2half(o_acc[1][reg] * inv);
  }
}

extern "C" void kernel_launch(void* const* d_in, const int* in_sizes, int n_in,
                              void* d_out, int out_size, void* d_ws, size_t ws_size,
                              hipStream_t stream) {
  // ---- Input mapping via in_sizes pattern (dict vs sorted-key order) ----
  int iq, ikv, iwq, iwk, iwv, iwo;
  bool ok = true;
  if (n_in >= 8 && in_sizes[0] == 8388608 && in_sizes[1] == 8388608) {
    iq = 0; ikv = 1; iwq = 4; iwk = 5; iwv = 6; iwo = 7;          // dict order
  } else if (n_in >= 8 && in_sizes[0] == 8388608 && in_sizes[1] == 8192) {
    ikv = 0; iq = 2; iwk = 4; iwo = 5; iwq = 6; iwv = 7;          // sorted keys
  } else if (n_in == 6 && in_sizes[2] == 1048576) {
    iq = 0; ikv = 1; iwq = 2; iwk = 3; iwv = 4; iwo = 5;          // dict, no masks
  } else if (n_in == 6 && in_sizes[2] == 262144) {
    ikv = 0; iq = 1; iwk = 2; iwo = 3; iwq = 4; iwv = 5;          // sorted, no masks
  } else {
    ok = false; iq = ikv = iwq = iwk = iwv = iwo = 0;
  }

  const size_t nQ  = (size_t)B_ * TQ * DM;
  const size_t nKV = (size_t)B_ * TKV * NKV * DK;
  const size_t nWq = (size_t)DM * DM;          // w_q / w_out elems
  const size_t nWk = (size_t)NKV * DK * DM;    // w_k / w_v elems
  const size_t need = (nQ + 2 * nKV + 2 * nWq + 2 * nWk) * sizeof(__half);
  if (!ok || ws_size < need) {
    zero_out_kernel<<<(out_size + 255) / 256, 256, 0, stream>>>((float*)d_out,
                                                                out_size);
    return;
  }

  const float* query     = (const float*)d_in[iq];
  const float* key_value = (const float*)d_in[ikv];
  const float* w_q   = (const float*)d_in[iwq];
  const float* w_k   = (const float*)d_in[iwk];
  const float* w_v   = (const float*)d_in[iwv];
  const float* w_out = (const float*)d_in[iwo];
  float* out = (float*)d_out;

  __half* Qh  = (__half*)d_ws;
  __half* Kh  = Qh + nQ;
  __half* Vh  = Kh + nKV;
  __half* wqh = Vh + nKV;
  __half* wkh = wqh + nWq;
  __half* wvh = wkh + nWk;
  __half* woh = wvh + nWk;

  dim3 blk(256);
  // One-shot weight conversion: 327,680 granules of 8 -> 1280 blocks
  cvt_weights<<<dim3(1280), blk, 0, stream>>>(w_q, w_k, w_v, w_out,
                                              wqh, wkh, wvh, woh);
  // Fused Q/K/V projections, one 1536-block launch (f16 weights):
  gemm_proj<<<dim3(1536), blk, 0, stream>>>(query, key_value, wqh, wkh, wvh,
                                            Qh, Kh, Vh, DM, NKV * DK, DM);
  int pk = B_ * TKV * NKV * 32;
  rope_kernel<<<(pk + 255) / 256, blk, 0, stream>>>(Kh, TKV, NKV, pk);
  // MFMA flash attention (32x32 frags, P-in-register, fused Q-rope)
  attn_mfma<<<dim3(TQ / 128, NH, B_), dim3(256), 0, stream>>>(Qh, Kh, Vh, Qh);
  // Output projection: M=8192, N=1024, K=1024, fp32 out (f16 A + f16 W)
  gemm_proj<<<dim3(1024), blk, 0, stream>>>(Qh, Qh, woh, woh, woh,
                                            out, out, out, DM, DM, DM);
}